// Round 10
// baseline (306.392 us; speedup 1.0000x reference)
//
#include <hip/hip_runtime.h>
#include <hip/hip_bf16.h>

#define NN 6144
#define INPUT 1024
#define HID 256

using frag  = __attribute__((ext_vector_type(8))) short;   // 8 bf16
using f32x4 = __attribute__((ext_vector_type(4))) float;

static __device__ __forceinline__ unsigned short bf16u(float x) {
    unsigned u = __float_as_uint(x);
    u += 0x7fff + ((u >> 16) & 1);     // RNE
    return (unsigned short)(u >> 16);
}

// async global->LDS (no VGPR dest: allocator cannot sink; gated by counted vmcnt)
static __device__ __forceinline__ void gll16(const void* g, void* l) {
    __builtin_amdgcn_global_load_lds((__attribute__((address_space(1))) const void*)g,
                                     (__attribute__((address_space(3))) void*)l, 16, 0, 0);
}

// LDS-producer barrier without the __syncthreads vmcnt(0) drain.
static __device__ __forceinline__ void lds_barrier() {
    asm volatile("s_waitcnt lgkmcnt(0)" ::: "memory");
    __builtin_amdgcn_s_barrier();
    __builtin_amdgcn_sched_barrier(0);
}

// ============ FRAG-ORDER TILE LAYOUT (r7) ============
// 16x32 bf16 tile as 1 KB: slot l = MFMA lane l's fragment (row l&15, k (l>>4)*8..+7)

// ---------------- prep: X -> Xbp (frag tiles), W -> Wtp (frag tiles) ----------------
__global__ __launch_bounds__(256) void k_prep(const float* __restrict__ X,
                                              const float* __restrict__ W,
                                              unsigned short* __restrict__ Xbp,
                                              unsigned short* __restrict__ Wtp) {
    int b = blockIdx.x;
    if (b < 3072) {                         // X: 6144 x 1024, thread -> (i, k8)
        int t = b * 256 + threadIdx.x;
        int i = t >> 7, k8 = t & 127;
        const float4* p = reinterpret_cast<const float4*>(X + (size_t)i * INPUT + k8 * 8);
        float4 x0 = p[0], x1 = p[1];
        frag v;
        v[0] = (short)bf16u(x0.x); v[1] = (short)bf16u(x0.y);
        v[2] = (short)bf16u(x0.z); v[3] = (short)bf16u(x0.w);
        v[4] = (short)bf16u(x1.x); v[5] = (short)bf16u(x1.y);
        v[6] = (short)bf16u(x1.z); v[7] = (short)bf16u(x1.w);
        size_t off = ((size_t)((i >> 4) * 32 + (k8 >> 2))) * 512 + (k8 & 3) * 128 + (i & 15) * 8;
        *reinterpret_cast<frag*>(Xbp + off) = v;
    } else {                                // W: 1024 x 256, thread -> (n, k8)
        int u = (b - 3072) * 256 + threadIdx.x;
        int n = u >> 7, k8 = u & 127;
        int k = k8 * 8;
        frag v;
#pragma unroll
        for (int e = 0; e < 8; e++) v[e] = (short)bf16u(W[(size_t)(k + e) * HID + n]);
        size_t off = ((size_t)((n >> 4) * 32 + (k8 >> 2))) * 512 + (k8 & 3) * 128 + (n & 15) * 8;
        *reinterpret_cast<frag*>(Wtp + off) = v;
    }
}

// ---------------- GEMM1 (unchanged r7): hTp frag-order + s1/s2 ----------------
__global__ __launch_bounds__(256, 4) void k_gemm1(const unsigned short* __restrict__ Xbp,
                                                  const unsigned short* __restrict__ Wtp,
                                                  const float* __restrict__ a_edge,
                                                  unsigned short* __restrict__ hTp,
                                                  float* __restrict__ s1,
                                                  float* __restrict__ s2) {
    int t = threadIdx.x;
    int w = t >> 6, l = t & 63, lm = l & 15, q = l >> 4;
    int bx = blockIdx.x, by = blockIdx.y;
    int i0 = bx * 32;
    int tn = by * 4 + w;

    const unsigned short* pA0 = Xbp + (size_t)(bx * 2) * 32 * 512 + l * 8;
    const unsigned short* pA1 = Xbp + (size_t)(bx * 2 + 1) * 32 * 512 + l * 8;
    const unsigned short* pB  = Wtp + (size_t)tn * 32 * 512 + l * 8;

    f32x4 acc0 = {}, acc1 = {};
    frag a0s[3], a1s[3], bs[3];
#pragma unroll
    for (int s = 0; s < 2; s++) {
        a0s[s] = *reinterpret_cast<const frag*>(pA0 + s * 512);
        a1s[s] = *reinterpret_cast<const frag*>(pA1 + s * 512);
        bs[s]  = *reinterpret_cast<const frag*>(pB  + s * 512);
    }
#pragma unroll
    for (int tk = 0; tk < 32; tk++) {
        int cur = tk % 3;
        if (tk < 30) {
            int nx = (tk + 2) % 3;
            a0s[nx] = *reinterpret_cast<const frag*>(pA0 + (tk + 2) * 512);
            a1s[nx] = *reinterpret_cast<const frag*>(pA1 + (tk + 2) * 512);
            bs[nx]  = *reinterpret_cast<const frag*>(pB  + (tk + 2) * 512);
        }
        acc0 = __builtin_amdgcn_mfma_f32_16x16x32_bf16(a0s[cur], bs[cur], acc0, 0, 0, 0);
        acc1 = __builtin_amdgcn_mfma_f32_16x16x32_bf16(a1s[cur], bs[cur], acc1, 0, 0, 0);
    }

    unsigned short* tb = hTp + ((size_t)bx * 16 + tn) * 512;
    ushort4 o;
    o.x = bf16u(acc0[0]); o.y = bf16u(acc0[1]); o.z = bf16u(acc0[2]); o.w = bf16u(acc0[3]);
    *reinterpret_cast<ushort4*>(tb + (q >> 1) * 128 + lm * 8 + (q & 1) * 4) = o;
    o.x = bf16u(acc1[0]); o.y = bf16u(acc1[1]); o.z = bf16u(acc1[2]); o.w = bf16u(acc1[3]);
    *reinterpret_cast<ushort4*>(tb + (2 + (q >> 1)) * 128 + lm * 8 + (q & 1) * 4) = o;

    float a1v = a_edge[tn * 16 + lm], a2v = a_edge[HID + tn * 16 + lm];
#pragma unroll
    for (int h = 0; h < 2; h++) {
        const f32x4& ac = h ? acc1 : acc0;
#pragma unroll
        for (int r = 0; r < 4; r++) {
            float v1 = ac[r] * a1v, v2 = ac[r] * a2v;
            v1 += __shfl_xor(v1, 1); v2 += __shfl_xor(v2, 1);
            v1 += __shfl_xor(v1, 2); v2 += __shfl_xor(v2, 2);
            v1 += __shfl_xor(v1, 4); v2 += __shfl_xor(v2, 4);
            v1 += __shfl_xor(v1, 8); v2 += __shfl_xor(v2, 8);
            if (lm == 0) {
                atomicAdd(&s1[i0 + h * 16 + q * 4 + r], v1);
                atomicAdd(&s2[i0 + h * 16 + q * 4 + r], v2);
            }
        }
    }
}

// ---------------- fused attention: M=64 rows/block (halved hTp re-read traffic) ----------------
// grid (96, 8) = 768 blocks; block 512 = 8 waves. Each block: 64 rows x j-eighth
// (768 cols) in 12 chunks of 64. bf (hTp) traffic per dispatch: 604 -> 302 MB --
// the same L2/TA mechanism that bought r6->r7's -20us. adjS staging is exactly
// WAVE-PRIVATE (wave w glls rows 8w..8w+7; builder threads t>>3 in [8w,8w+7] ARE
// wave w) -> no staging barrier; ONE lds_barrier per chunk (P only). Issue order
// per chunk: bf[4], s2[2], vmcnt(6) [retires exactly gll(c)], stage gll(c+1)[2],
// build P (s2-wait vmcnt(2) keeps gll(c+1) in flight), lds_barrier, 16 MFMA.
__global__ __launch_bounds__(512, 2) void k_attn(const int* __restrict__ adj,
                                                 const float* __restrict__ s1,
                                                 const float* __restrict__ s2,
                                                 const unsigned short* __restrict__ hTp,
                                                 float* __restrict__ U8,
                                                 float* __restrict__ denom8) {
    __shared__ unsigned short P[2][64][72];    // 18432 B (72 pad: +4-bank row shift)
    __shared__ int adjS[2][64][64];            // 32768 B, linear gll dest, wave-private rows
    int t = threadIdx.x;
    int m = t >> 3, cg = t & 7;                // builder: row m (0..63), col-group cg (8 cols)
    int i0 = blockIdx.x * 64;
    int q8 = blockIdx.y, j0 = q8 * 768;
    int w = t >> 6, l = t & 63, lm = l & 15, q = l >> 4;

    float s1v = s1[i0 + m];
    // staging: wave w stages adj rows 8w..8w+7, 64 cols (2 gll16 x 4 rows each)
    const int* astage = adj + (size_t)(i0 + w * 8 + (l >> 4)) * NN + j0 + (l & 15) * 4;
    const float* s2p = s2 + j0 + cg * 8;       // builder-lane direct (L1-hot)

    // dense B-frag base: tile (tj = q8*24 + c*2 + kk, tn = w*2 + nt)
    const unsigned short* hb = hTp + ((size_t)(q8 * 24) * 16 + w * 2) * 512 + l * 8;

    f32x4 acc[4][2] = {};
    float dsum = 0.f;

#define STAGE(JC, BUF) { \
        gll16(astage + (JC), &adjS[BUF][w * 8][0]); \
        gll16(astage + (JC) + 4 * NN, &adjS[BUF][w * 8 + 4][0]); }

    STAGE(0, 0)

    for (int c = 0; c < 12; c++) {
        int buf = c & 1, jc = c * 64;

        // ---- this chunk's 4 dense B-frags (1KB wave loads), then s2 ----
        frag bf[4];
#pragma unroll
        for (int kk = 0; kk < 2; kk++)
#pragma unroll
            for (int nt = 0; nt < 2; nt++)
                bf[kk * 2 + nt] = *reinterpret_cast<const frag*>(
                    hb + ((size_t)(c * 2 + kk) * 16 + nt) * 512);
        float4 sv0 = *reinterpret_cast<const float4*>(s2p + jc);
        float4 sv1 = *reinterpret_cast<const float4*>(s2p + jc + 4);

        // outstanding: gll(c)[2, oldest] + bf[4] + s2[2] = 8 -> vmcnt(6) retires
        // exactly gll(c). adjS is wave-private: no barrier needed here.
        asm volatile("s_waitcnt vmcnt(6)" ::: "memory");
        __builtin_amdgcn_sched_barrier(0);
        if (c < 11) STAGE(jc + 64, buf ^ 1)    // adjS[buf^1] readers passed lds_barrier(c-1)

        // ---- build P[buf] rows (wave-private adjS + s2 regs) ----
        {
            const int* aL = &adjS[buf][m][cg * 8];
            int4 av0 = *reinterpret_cast<const int4*>(aL);
            int4 av1 = *reinterpret_cast<const int4*>(aL + 4);
            float sc, wv, p0, p1, p2, p3, p4, p5, p6, p7;
            sc = s1v + sv0.x; wv = fmaxf(sc, 0.2f * sc); p0 = av0.x ? __expf(wv) : 0.f;
            sc = s1v + sv0.y; wv = fmaxf(sc, 0.2f * sc); p1 = av0.y ? __expf(wv) : 0.f;
            sc = s1v + sv0.z; wv = fmaxf(sc, 0.2f * sc); p2 = av0.z ? __expf(wv) : 0.f;
            sc = s1v + sv0.w; wv = fmaxf(sc, 0.2f * sc); p3 = av0.w ? __expf(wv) : 0.f;
            sc = s1v + sv1.x; wv = fmaxf(sc, 0.2f * sc); p4 = av1.x ? __expf(wv) : 0.f;
            sc = s1v + sv1.y; wv = fmaxf(sc, 0.2f * sc); p5 = av1.y ? __expf(wv) : 0.f;
            sc = s1v + sv1.z; wv = fmaxf(sc, 0.2f * sc); p6 = av1.z ? __expf(wv) : 0.f;
            sc = s1v + sv1.w; wv = fmaxf(sc, 0.2f * sc); p7 = av1.w ? __expf(wv) : 0.f;
            dsum += ((p0 + p1) + (p2 + p3)) + ((p4 + p5) + (p6 + p7));
            frag pk;
            pk[0] = (short)bf16u(p0); pk[1] = (short)bf16u(p1);
            pk[2] = (short)bf16u(p2); pk[3] = (short)bf16u(p3);
            pk[4] = (short)bf16u(p4); pk[5] = (short)bf16u(p5);
            pk[6] = (short)bf16u(p6); pk[7] = (short)bf16u(p7);
            *reinterpret_cast<frag*>(&P[buf][m][cg * 8]) = pk;
        }

        // single barrier per chunk: P[buf] visible block-wide (P[buf] was last read
        // at MFMA(c-2), separated by lds_barrier(c-1)).
        lds_barrier();

        // ---- consume: 2 k-steps x (4 A-halves x 2 B-frags) = 16 MFMA/wave ----
        __builtin_amdgcn_s_setprio(1);
#pragma unroll
        for (int kk = 0; kk < 2; kk++) {
            frag a0 = *reinterpret_cast<const frag*>(&P[buf][lm][kk * 32 + q * 8]);
            frag a1 = *reinterpret_cast<const frag*>(&P[buf][16 + lm][kk * 32 + q * 8]);
            frag a2 = *reinterpret_cast<const frag*>(&P[buf][32 + lm][kk * 32 + q * 8]);
            frag a3 = *reinterpret_cast<const frag*>(&P[buf][48 + lm][kk * 32 + q * 8]);
#pragma unroll
            for (int nt = 0; nt < 2; nt++) {
                acc[0][nt] = __builtin_amdgcn_mfma_f32_16x16x32_bf16(a0, bf[kk * 2 + nt], acc[0][nt], 0, 0, 0);
                acc[1][nt] = __builtin_amdgcn_mfma_f32_16x16x32_bf16(a1, bf[kk * 2 + nt], acc[1][nt], 0, 0, 0);
                acc[2][nt] = __builtin_amdgcn_mfma_f32_16x16x32_bf16(a2, bf[kk * 2 + nt], acc[2][nt], 0, 0, 0);
                acc[3][nt] = __builtin_amdgcn_mfma_f32_16x16x32_bf16(a3, bf[kk * 2 + nt], acc[3][nt], 0, 0, 0);
            }
        }
        __builtin_amdgcn_s_setprio(0);
    }
#undef STAGE

    // denom partial: builder lanes with same m are cg=0..7 (consecutive) -> reduce over cg
    float v = dsum;
    v += __shfl_xor(v, 1); v += __shfl_xor(v, 2); v += __shfl_xor(v, 4);
    if (cg == 0) denom8[(size_t)q8 * NN + i0 + m] = v;

    // U8 partial: plain stores (64B-dense per 16-lane group)
    float* Ub = U8 + (size_t)q8 * NN * HID;
#pragma unroll
    for (int h = 0; h < 4; h++)
#pragma unroll
        for (int nt = 0; nt < 2; nt++)
#pragma unroll
            for (int r = 0; r < 4; r++)
                Ub[(size_t)(i0 + h * 16 + q * 4 + r) * HID + w * 32 + nt * 16 + lm] = acc[h][nt][r];
}

// ---------------- normalize: out = (sum_q8 U8) / (sum_q8 denom8) ----------------
__global__ __launch_bounds__(256) void k_norm(const float* __restrict__ U8,
                                              const float* __restrict__ denom8,
                                              float* __restrict__ out) {
    int i = blockIdx.x, t = threadIdx.x;
    size_t S = (size_t)NN * HID;
    size_t base = (size_t)i * HID + t;
    float u = 0.f, d = 0.f;
#pragma unroll
    for (int s = 0; s < 8; s++) {
        u += U8[base + s * S];
        d += denom8[i + s * NN];
    }
    out[base] = (d != 0.f) ? u / d : 0.f;
}

extern "C" void kernel_launch(void* const* d_in, const int* in_sizes, int n_in,
                              void* d_out, int out_size, void* d_ws, size_t ws_size,
                              hipStream_t stream) {
    const float* X      = (const float*)d_in[0];   // 6144x1024
    const float* W      = (const float*)d_in[1];   // 1024x256
    const float* a_edge = (const float*)d_in[2];   // 512
    const int*   adj    = (const int*)d_in[3];     // 6144x6144
    float* out = (float*)d_out;

    float* U8     = (float*)d_ws;                          // 8*NN*HID f32 (50.3 MB)
    float* denom8 = U8 + (size_t)8 * NN * HID;             // 8*NN
    float* s1     = denom8 + (size_t)8 * NN;               // NN
    float* s2     = s1 + NN;                               // NN
    unsigned short* hTp = (unsigned short*)(s2 + NN);      // frag tiles (3.1 MB)
    unsigned short* Wtp = hTp + (size_t)HID * NN;          // frag tiles (0.5 MB)
    // Xbp (12.6 MB) ALIASES U8: dead before k_attn fully overwrites U8.
    unsigned short* Xbp = (unsigned short*)U8;

    hipMemsetAsync(s1, 0, 2 * NN * sizeof(float), stream);
    k_prep<<<3072 + 128, 256, 0, stream>>>(X, W, Xbp, Wtp);
    k_gemm1<<<dim3(NN / 32, 4), 256, 0, stream>>>(Xbp, Wtp, a_edge, hTp, s1, s2);
    k_attn<<<dim3(NN / 64, 8), 512, 0, stream>>>(adj, s1, s2, hTp, U8, denom8);
    k_norm<<<NN, 256, 0, stream>>>(U8, denom8, out);
}

// Round 11
// 288.605 us; speedup vs baseline: 1.0616x; 1.0616x over previous
//
#include <hip/hip_runtime.h>
#include <hip/hip_bf16.h>

#define NN 6144
#define INPUT 1024
#define HID 256

using frag  = __attribute__((ext_vector_type(8))) short;   // 8 bf16
using f32x4 = __attribute__((ext_vector_type(4))) float;

static __device__ __forceinline__ unsigned short bf16u(float x) {
    unsigned u = __float_as_uint(x);
    u += 0x7fff + ((u >> 16) & 1);     // RNE
    return (unsigned short)(u >> 16);
}

// async global->LDS (no VGPR dest; compiler cannot sink; gated by OUR counted vmcnt)
static __device__ __forceinline__ void gll16(const void* g, void* l) {
    __builtin_amdgcn_global_load_lds((__attribute__((address_space(1))) const void*)g,
                                     (__attribute__((address_space(3))) void*)l, 16, 0, 0);
}
static __device__ __forceinline__ void gll4(const void* g, void* l) {
    __builtin_amdgcn_global_load_lds((__attribute__((address_space(1))) const void*)g,
                                     (__attribute__((address_space(3))) void*)l, 4, 0, 0);
}

// LDS-producer barrier without the __syncthreads vmcnt(0) drain.
static __device__ __forceinline__ void lds_barrier() {
    asm volatile("s_waitcnt lgkmcnt(0)" ::: "memory");
    __builtin_amdgcn_s_barrier();
    __builtin_amdgcn_sched_barrier(0);
}

// ============ FRAG-ORDER TILE LAYOUT ============
// A 16x32 bf16 operand tile (16 rows x 32 k) is stored as 1 KB where 16-B slot l
// holds exactly MFMA lane l's fragment: row = l&15, k = (l>>4)*8 .. +7.
// -> every operand load is ONE dense 1KB wave read (16 cache lines) instead of
//    64 scattered 16B segments across 16 rows (the r0-r6 invariant bottleneck).

// ---------------- prep: X -> Xbp (frag tiles), W -> Wtp (frag tiles) ----------------
__global__ __launch_bounds__(256) void k_prep(const float* __restrict__ X,
                                              const float* __restrict__ W,
                                              unsigned short* __restrict__ Xbp,
                                              unsigned short* __restrict__ Wtp) {
    int b = blockIdx.x;
    if (b < 3072) {                         // X: 6144 x 1024, thread -> (i, k8)
        int t = b * 256 + threadIdx.x;
        int i = t >> 7, k8 = t & 127;
        const float4* p = reinterpret_cast<const float4*>(X + (size_t)i * INPUT + k8 * 8);
        float4 x0 = p[0], x1 = p[1];
        frag v;
        v[0] = (short)bf16u(x0.x); v[1] = (short)bf16u(x0.y);
        v[2] = (short)bf16u(x0.z); v[3] = (short)bf16u(x0.w);
        v[4] = (short)bf16u(x1.x); v[5] = (short)bf16u(x1.y);
        v[6] = (short)bf16u(x1.z); v[7] = (short)bf16u(x1.w);
        size_t off = ((size_t)((i >> 4) * 32 + (k8 >> 2))) * 512 + (k8 & 3) * 128 + (i & 15) * 8;
        *reinterpret_cast<frag*>(Xbp + off) = v;
    } else {                                // W: 1024 x 256, thread -> (n, k8)
        int u = (b - 3072) * 256 + threadIdx.x;
        int n = u >> 7, k8 = u & 127;
        int k = k8 * 8;
        frag v;
#pragma unroll
        for (int e = 0; e < 8; e++) v[e] = (short)bf16u(W[(size_t)(k + e) * HID + n]);
        size_t off = ((size_t)((n >> 4) * 32 + (k8 >> 2))) * 512 + (k8 & 3) * 128 + (n & 15) * 8;
        *reinterpret_cast<frag*>(Wtp + off) = v;
    }
}

// ---------------- GEMM1: hTp = frag-order (X @ W)^T, + fused s1/s2 ----------------
// LDS-FREE. grid (192,4); block 256 = 4 waves, independent. Wave: M=32 (2 A-tiles),
// N=16 (tile tn = by*4+w), K=1024 = 32 frag-tiles. ALL reads are dense 1KB wave
// loads, sequential in tk. 3-set rotated register pipeline (depth 2).
__global__ __launch_bounds__(256, 4) void k_gemm1(const unsigned short* __restrict__ Xbp,
                                                  const unsigned short* __restrict__ Wtp,
                                                  const float* __restrict__ a_edge,
                                                  unsigned short* __restrict__ hTp,
                                                  float* __restrict__ s1,
                                                  float* __restrict__ s2) {
    int t = threadIdx.x;
    int w = t >> 6, l = t & 63, lm = l & 15, q = l >> 4;
    int bx = blockIdx.x, by = blockIdx.y;
    int i0 = bx * 32;
    int tn = by * 4 + w;

    const unsigned short* pA0 = Xbp + (size_t)(bx * 2) * 32 * 512 + l * 8;
    const unsigned short* pA1 = Xbp + (size_t)(bx * 2 + 1) * 32 * 512 + l * 8;
    const unsigned short* pB  = Wtp + (size_t)tn * 32 * 512 + l * 8;

    f32x4 acc0 = {}, acc1 = {};
    frag a0s[3], a1s[3], bs[3];
#pragma unroll
    for (int s = 0; s < 2; s++) {
        a0s[s] = *reinterpret_cast<const frag*>(pA0 + s * 512);
        a1s[s] = *reinterpret_cast<const frag*>(pA1 + s * 512);
        bs[s]  = *reinterpret_cast<const frag*>(pB  + s * 512);
    }
#pragma unroll
    for (int tk = 0; tk < 32; tk++) {
        int cur = tk % 3;
        if (tk < 30) {
            int nx = (tk + 2) % 3;
            a0s[nx] = *reinterpret_cast<const frag*>(pA0 + (tk + 2) * 512);
            a1s[nx] = *reinterpret_cast<const frag*>(pA1 + (tk + 2) * 512);
            bs[nx]  = *reinterpret_cast<const frag*>(pB  + (tk + 2) * 512);
        }
        acc0 = __builtin_amdgcn_mfma_f32_16x16x32_bf16(a0s[cur], bs[cur], acc0, 0, 0, 0);
        acc1 = __builtin_amdgcn_mfma_f32_16x16x32_bf16(a1s[cur], bs[cur], acc1, 0, 0, 0);
    }

    unsigned short* tb = hTp + ((size_t)bx * 16 + tn) * 512;
    ushort4 o;
    o.x = bf16u(acc0[0]); o.y = bf16u(acc0[1]); o.z = bf16u(acc0[2]); o.w = bf16u(acc0[3]);
    *reinterpret_cast<ushort4*>(tb + (q >> 1) * 128 + lm * 8 + (q & 1) * 4) = o;
    o.x = bf16u(acc1[0]); o.y = bf16u(acc1[1]); o.z = bf16u(acc1[2]); o.w = bf16u(acc1[3]);
    *reinterpret_cast<ushort4*>(tb + (2 + (q >> 1)) * 128 + lm * 8 + (q & 1) * 4) = o;

    float a1v = a_edge[tn * 16 + lm], a2v = a_edge[HID + tn * 16 + lm];
#pragma unroll
    for (int h = 0; h < 2; h++) {
        const f32x4& ac = h ? acc1 : acc0;
#pragma unroll
        for (int r = 0; r < 4; r++) {
            float v1 = ac[r] * a1v, v2 = ac[r] * a2v;
            v1 += __shfl_xor(v1, 1); v2 += __shfl_xor(v2, 1);
            v1 += __shfl_xor(v1, 2); v2 += __shfl_xor(v2, 2);
            v1 += __shfl_xor(v1, 4); v2 += __shfl_xor(v2, 4);
            v1 += __shfl_xor(v1, 8); v2 += __shfl_xor(v2, 8);
            if (lm == 0) {
                atomicAdd(&s1[i0 + h * 16 + q * 4 + r], v1);
                atomicAdd(&s2[i0 + h * 16 + q * 4 + r], v2);
            }
        }
    }
}

// ---------------- fused attention (best-known, round-7-benched: attn ~83-86us) ----------------
// grid (192,4); block 512 = 8 waves. gll-staged adj/s2 one chunk ahead (zero-VGPR,
// unsinkable), counted vmcnt(8) gate (never drains), dense bf from frag-order hTp,
// P double-buffer with one lds-only barrier pair per chunk.
__global__ __launch_bounds__(512, 2) void k_attn(const int* __restrict__ adj,
                                                 const float* __restrict__ s1,
                                                 const float* __restrict__ s2,
                                                 const unsigned short* __restrict__ hTp,
                                                 float* __restrict__ U4,
                                                 float* __restrict__ denom4) {
    __shared__ unsigned short P[2][32][136];   // 17408 B
    __shared__ int   adjS[2][32][128];         // 32768 B, linear (gll dest)
    __shared__ float s2S[2][128];              // 1024 B
    int t = threadIdx.x;
    int m = t >> 4, cg = t & 15;               // builder: row m (0..31), col-group cg
    int i0 = blockIdx.x * 32;
    int q4 = blockIdx.y, j0 = q4 * 1536;
    int w = t >> 6, l = t & 63, lm = l & 15, q = l >> 4;

    float s1v = s1[i0 + m];
    const int*   astage = adj + (size_t)(i0 + w * 4 + (l >> 5)) * NN + j0 + (l & 31) * 4;
    const float* sstage = s2 + j0 + w * 16 + l;    // only lanes l<16 issue

    // dense B-frag base: tile (tj, tn = w*2+nt) at (tj*16 + tn)*512 + l*8 ushorts
    const unsigned short* hb = hTp + (size_t)(w * 2) * 512 + l * 8;
    int tjb = q4 * 48;

    f32x4 acc[2][2] = {};
    float dsum = 0.f;

#define STAGE(JC, BUF) { \
        gll16(astage + (JC), &adjS[BUF][w * 4][0]); \
        gll16(astage + (JC) + 2 * NN, &adjS[BUF][w * 4 + 2][0]); \
        if (l < 16) gll4(sstage + (JC), &s2S[BUF][w * 16]); }

    STAGE(0, 0)

    for (int c = 0; c < 12; c++) {
        int buf = c & 1, jc = c * 128;

        // ---- this chunk's 8 B-frags: DENSE 1KB wave loads ----
        frag bf[8];
#pragma unroll
        for (int kk = 0; kk < 4; kk++)
#pragma unroll
            for (int nt = 0; nt < 2; nt++)
                bf[kk * 2 + nt] = *reinterpret_cast<const frag*>(
                    hb + ((size_t)(tjb + c * 4 + kk) * 16 + nt) * 512);

        // outstanding: gll(c)[3, oldest] + bf[8] = 11 -> vmcnt(8) retires exactly gll(c)
        asm volatile("s_waitcnt vmcnt(8)" ::: "memory");
        __builtin_amdgcn_s_barrier();              // adjS[buf]/s2S[buf] ready block-wide
        __builtin_amdgcn_sched_barrier(0);
        if (c < 11) STAGE(jc + 128, buf ^ 1)       // after barrier: prev readers done

        // ---- build P[buf] from staged LDS (VALU only, no global waits) ----
        {
            const int*   aL = &adjS[buf][m][cg * 8];
            const float* sL = &s2S[buf][cg * 8];
            int4   av0 = *reinterpret_cast<const int4*>(aL);
            int4   av1 = *reinterpret_cast<const int4*>(aL + 4);
            float4 sv0 = *reinterpret_cast<const float4*>(sL);
            float4 sv1 = *reinterpret_cast<const float4*>(sL + 4);
            float sc, wv, p0, p1, p2, p3, p4, p5, p6, p7;
            sc = s1v + sv0.x; wv = fmaxf(sc, 0.2f * sc); p0 = av0.x ? __expf(wv) : 0.f;
            sc = s1v + sv0.y; wv = fmaxf(sc, 0.2f * sc); p1 = av0.y ? __expf(wv) : 0.f;
            sc = s1v + sv0.z; wv = fmaxf(sc, 0.2f * sc); p2 = av0.z ? __expf(wv) : 0.f;
            sc = s1v + sv0.w; wv = fmaxf(sc, 0.2f * sc); p3 = av0.w ? __expf(wv) : 0.f;
            sc = s1v + sv1.x; wv = fmaxf(sc, 0.2f * sc); p4 = av1.x ? __expf(wv) : 0.f;
            sc = s1v + sv1.y; wv = fmaxf(sc, 0.2f * sc); p5 = av1.y ? __expf(wv) : 0.f;
            sc = s1v + sv1.z; wv = fmaxf(sc, 0.2f * sc); p6 = av1.z ? __expf(wv) : 0.f;
            sc = s1v + sv1.w; wv = fmaxf(sc, 0.2f * sc); p7 = av1.w ? __expf(wv) : 0.f;
            dsum += ((p0 + p1) + (p2 + p3)) + ((p4 + p5) + (p6 + p7));
            frag pk;
            pk[0] = (short)bf16u(p0); pk[1] = (short)bf16u(p1);
            pk[2] = (short)bf16u(p2); pk[3] = (short)bf16u(p3);
            pk[4] = (short)bf16u(p4); pk[5] = (short)bf16u(p5);
            pk[6] = (short)bf16u(p6); pk[7] = (short)bf16u(p7);
            *reinterpret_cast<frag*>(&P[buf][m][cg * 8]) = pk;
        }

        lds_barrier();

        // ---- consume: 4 k-steps x (2 A-halves x 2 B-frags) = 16 MFMA/wave ----
        __builtin_amdgcn_s_setprio(1);
#pragma unroll
        for (int kk = 0; kk < 4; kk++) {
            frag a0 = *reinterpret_cast<const frag*>(&P[buf][lm][kk * 32 + q * 8]);
            frag a1 = *reinterpret_cast<const frag*>(&P[buf][16 + lm][kk * 32 + q * 8]);
#pragma unroll
            for (int nt = 0; nt < 2; nt++) {
                acc[0][nt] = __builtin_amdgcn_mfma_f32_16x16x32_bf16(a0, bf[kk * 2 + nt], acc[0][nt], 0, 0, 0);
                acc[1][nt] = __builtin_amdgcn_mfma_f32_16x16x32_bf16(a1, bf[kk * 2 + nt], acc[1][nt], 0, 0, 0);
            }
        }
        __builtin_amdgcn_s_setprio(0);
    }
#undef STAGE

    // denom partial: lanes with same m are cg=0..15 -> reduce over cg
    float v = dsum;
    v += __shfl_xor(v, 1); v += __shfl_xor(v, 2);
    v += __shfl_xor(v, 4); v += __shfl_xor(v, 8);
    if (cg == 0) denom4[(size_t)q4 * NN + i0 + m] = v;

    // U4 partial: plain stores (64B-dense per 16-lane group)
    float* Ub = U4 + (size_t)q4 * NN * HID;
#pragma unroll
    for (int h = 0; h < 2; h++)
#pragma unroll
        for (int nt = 0; nt < 2; nt++)
#pragma unroll
            for (int r = 0; r < 4; r++)
                Ub[(size_t)(i0 + h * 16 + q * 4 + r) * HID + w * 32 + nt * 16 + lm] = acc[h][nt][r];
}

// ---------------- normalize: out = (sum_q U4) / (sum_q denom4) ----------------
__global__ __launch_bounds__(256) void k_norm(const float* __restrict__ U4,
                                              const float* __restrict__ denom4,
                                              float* __restrict__ out) {
    int i = blockIdx.x, t = threadIdx.x;
    size_t S = (size_t)NN * HID;
    size_t base = (size_t)i * HID + t;
    float u = U4[base] + U4[base + S] + U4[base + 2 * S] + U4[base + 3 * S];
    float d = denom4[i] + denom4[i + NN] + denom4[i + 2 * NN] + denom4[i + 3 * NN];
    out[base] = (d != 0.f) ? u / d : 0.f;
}

extern "C" void kernel_launch(void* const* d_in, const int* in_sizes, int n_in,
                              void* d_out, int out_size, void* d_ws, size_t ws_size,
                              hipStream_t stream) {
    const float* X      = (const float*)d_in[0];   // 6144x1024
    const float* W      = (const float*)d_in[1];   // 1024x256
    const float* a_edge = (const float*)d_in[2];   // 512
    const int*   adj    = (const int*)d_in[3];     // 6144x6144
    float* out = (float*)d_out;

    float* U4     = (float*)d_ws;                          // 4*NN*HID f32 (25.2 MB)
    float* denom4 = U4 + (size_t)4 * NN * HID;             // 4*NN
    float* s1     = denom4 + (size_t)4 * NN;               // NN
    float* s2     = s1 + NN;                               // NN
    unsigned short* hTp = (unsigned short*)(s2 + NN);      // frag tiles (3.1 MB)
    unsigned short* Wtp = hTp + (size_t)HID * NN;          // frag tiles (0.5 MB)
    // Xbp (12.6 MB) ALIASES U4: dead before k_attn fully overwrites U4.
    unsigned short* Xbp = (unsigned short*)U4;

    hipMemsetAsync(s1, 0, 2 * NN * sizeof(float), stream);
    k_prep<<<3072 + 128, 256, 0, stream>>>(X, W, Xbp, Wtp);
    k_gemm1<<<dim3(NN / 32, 4), 256, 0, stream>>>(Xbp, Wtp, a_edge, hTp, s1, s2);
    k_attn<<<dim3(NN / 32, 4), 512, 0, stream>>>(adj, s1, s2, hTp, U4, denom4);
    k_norm<<<NN / 32 * 32, 256, 0, stream>>>(U4, denom4, out);
}